// Round 4
// baseline (167.958 us; speedup 1.0000x reference)
//
#include <hip/hip_runtime.h>
#include <math.h>

#define L_SEQ   16384
#define DMODEL  1024
#define NST     512             // complex states
#define CHUNK   128
#define NCHUNK  (L_SEQ / CHUNK) // 128

typedef float  f32x4 __attribute__((ext_vector_type(4)));
typedef short  s16x8 __attribute__((ext_vector_type(8)));

__device__ __forceinline__ unsigned short f2bf(float f) {      // RNE
    union { float f; unsigned int u; } v; v.f = f;
    unsigned int r = v.u + 0x7fffu + ((v.u >> 16) & 1u);
    return (unsigned short)(r >> 16);
}
__device__ __forceinline__ unsigned short f2bf_fast(float f) { // round-half-up (staging)
    union { float f; unsigned int u; } v; v.f = f;
    return (unsigned short)((v.u + 0x8000u) >> 16);
}
__device__ __forceinline__ float bf2f(unsigned int h16) {
    union { unsigned int u; float f; } v; v.u = h16 << 16; return v.f;
}
__device__ __forceinline__ void mfma16(f32x4& d, s16x8 a, s16x8 b) {
    asm volatile("v_mfma_f32_16x16x32_bf16 %0, %1, %2, %0"
                 : "+v"(d) : "v"(a), "v"(b));
}
__device__ __forceinline__ uint4 pack8(float4 x, float4 y) {
    union { unsigned short u[8]; uint4 v; } t;
    t.u[0] = f2bf_fast(x.x); t.u[1] = f2bf_fast(x.y);
    t.u[2] = f2bf_fast(x.z); t.u[3] = f2bf_fast(x.w);
    t.u[4] = f2bf_fast(y.x); t.u[5] = f2bf_fast(y.y);
    t.u[6] = f2bf_fast(y.z); t.u[7] = f2bf_fast(y.w);
    return t.v;
}

// ---------------- setup: lambda, lambda^128, gamma ----------------
__global__ void setup_params(const float* __restrict__ nu_log,
                             const float* __restrict__ theta_log,
                             const float* __restrict__ gamma_log,
                             float* __restrict__ lam,    // [2][512]
                             float* __restrict__ lamT,   // lambda^128
                             float* __restrict__ gam) {
    int s = threadIdx.x;
    if (s >= NST) return;
    float mod = expf(-expf(nu_log[s]));
    float th  = expf(theta_log[s]);
    float ar = mod * cosf(th);
    float ai = mod * sinf(th);
    lam[s] = ar; lam[NST + s] = ai;
    gam[s] = expf(gamma_log[s]);
    float pr = 1.f, pi = 0.f;
    for (int i = 0; i < CHUNK; ++i) {
        float nr = pr * ar - pi * ai;
        float ni = pr * ai + pi * ar;
        pr = nr; pi = ni;
    }
    lamT[s] = pr; lamT[NST + s] = pi;
}

// W1 row 2s = Bre[s,:], row 2s+1 = Bim[s,:]  (NO gamma — applied in scan, fp32)
__global__ void pack_w1(const float* __restrict__ Bre, const float* __restrict__ Bim,
                        unsigned short* __restrict__ W1) {
    int idx = blockIdx.x * 256 + threadIdx.x;
    int n = idx >> 10, k = idx & 1023;
    int s = n >> 1;
    float v = (n & 1) ? Bim[s * DMODEL + k] : Bre[s * DMODEL + k];
    W1[idx] = f2bf(v);
}
// W2[n][2s] = Cre[n][s], W2[n][2s+1] = -Cim[n][s]
__global__ void pack_w2(const float* __restrict__ Cre, const float* __restrict__ Cim,
                        unsigned short* __restrict__ W2) {
    int idx = blockIdx.x * 256 + threadIdx.x;
    int n = idx >> 10, k = idx & 1023;
    int s = k >> 1;
    float v = (k & 1) ? -Cim[n * NST + s] : Cre[n * NST + s];
    W2[idx] = f2bf(v);
}

// ---------- GEMM1: Bu = X @ W1^T  (X fp32 -> bf16 in-register) ----------
__global__ __launch_bounds__(256)
void gemm1(const float* __restrict__ X, const unsigned short* __restrict__ W1,
           unsigned short* __restrict__ Bu) {
    const int K = 1024;
    __shared__ __align__(16) unsigned short As[128 * 32];
    __shared__ __align__(16) unsigned short Bs[128 * 32];

    const int tid  = threadIdx.x;
    const int lane = tid & 63;
    const int wave = tid >> 6;
    const int wr   = wave >> 1, wc = wave & 1;

    const int lin   = blockIdx.y * gridDim.x + blockIdx.x;   // nwg=1024, %8==0
    const int n_new = (lin & 7) * 128 + (lin >> 3);
    const int bx = n_new & 7, by = n_new >> 3;
    const int m0 = by * 128, n0 = bx * 128;

    const int srow = tid >> 2;
    const int skb  = (tid & 3) * 8;

    const float*          Ag0 = X  + (size_t)(m0 + srow) * K + skb;
    const float*          Ag1 = Ag0 + (size_t)64 * K;
    const unsigned short* Bg0 = W1 + (size_t)(n0 + srow) * K + skb;
    const unsigned short* Bg1 = Bg0 + (size_t)64 * K;

    f32x4 acc[4][4] = {};

    float4 a00 = *(const float4*)(Ag0);
    float4 a01 = *(const float4*)(Ag0 + 4);
    float4 a10 = *(const float4*)(Ag1);
    float4 a11 = *(const float4*)(Ag1 + 4);
    uint4  rb0 = *(const uint4*)(Bg0);
    uint4  rb1 = *(const uint4*)(Bg1);

    const int fr = lane & 15;
    const int fk = (lane >> 4) * 8;

    for (int k0 = 0; k0 < K; k0 += 32) {
        __syncthreads();
        *(uint4*)&As[srow * 32 + skb]        = pack8(a00, a01);
        *(uint4*)&As[(64 + srow) * 32 + skb] = pack8(a10, a11);
        *(uint4*)&Bs[srow * 32 + skb]        = rb0;
        *(uint4*)&Bs[(64 + srow) * 32 + skb] = rb1;
        __syncthreads();
        if (k0 + 32 < K) {
            a00 = *(const float4*)(Ag0 + k0 + 32);
            a01 = *(const float4*)(Ag0 + k0 + 36);
            a10 = *(const float4*)(Ag1 + k0 + 32);
            a11 = *(const float4*)(Ag1 + k0 + 36);
            rb0 = *(const uint4*)(Bg0 + k0 + 32);
            rb1 = *(const uint4*)(Bg1 + k0 + 32);
        }
        s16x8 af[4], bfq[4];
        #pragma unroll
        for (int i = 0; i < 4; ++i)
            af[i] = *(const s16x8*)&As[(wr * 64 + i * 16 + fr) * 32 + fk];
        #pragma unroll
        for (int j = 0; j < 4; ++j)
            bfq[j] = *(const s16x8*)&Bs[(wc * 64 + j * 16 + fr) * 32 + fk];
        #pragma unroll
        for (int i = 0; i < 4; ++i)
            #pragma unroll
            for (int j = 0; j < 4; ++j)
                mfma16(acc[i][j], af[i], bfq[j]);
    }

    const int crow = (lane >> 4) * 4;
    const int ccol = lane & 15;
    #pragma unroll
    for (int i = 0; i < 4; ++i)
        #pragma unroll
        for (int j = 0; j < 4; ++j) {
            const int mbase = m0 + wr * 64 + i * 16 + crow;
            const int n     = n0 + wc * 64 + j * 16 + ccol;
            #pragma unroll
            for (int r = 0; r < 4; ++r)
                Bu[(size_t)(mbase + r) * 1024 + n] = f2bf(acc[i][j][r]);
        }
}

// ---------- scan pass 1: chunk ends only (recompute style) ----------
// Bu bf16 pairs viewed as uint; h = lam*h + gam*bu, 128 steps; write end.
__global__ __launch_bounds__(128)
void scan_ends(const unsigned int* __restrict__ Bu, const float* __restrict__ lam,
               const float* __restrict__ gam, float* __restrict__ ends) {
    const int s = blockIdx.y * 128 + threadIdx.x;
    const int c = blockIdx.x;
    const float lr = lam[s], li = lam[NST + s], g = gam[s];
    float hr = 0.f, hi = 0.f;
    size_t base = (size_t)c * CHUNK * NST + s;
    #pragma unroll 4
    for (int t = 0; t < CHUNK; ++t) {
        unsigned int v = Bu[base + (size_t)t * NST];
        float br = g * bf2f(v & 0xffffu);
        float bi = g * bf2f(v >> 16);
        float nr = fmaf(lr, hr, fmaf(-li, hi, br));
        float ni = fmaf(lr, hi, fmaf( li, hr, bi));
        hr = nr; hi = ni;
    }
    ends[(size_t)(c * NST + s) * 2]     = hr;
    ends[(size_t)(c * NST + s) * 2 + 1] = hi;
}

// ---------- carry scan across chunks ----------
__global__ __launch_bounds__(NST)
void scan_carry(const float* __restrict__ ends, const float* __restrict__ lamT,
                float* __restrict__ car) {
    const int s = threadIdx.x;
    const float ar = lamT[s], ai = lamT[NST + s];
    float cr = 0.f, ci = 0.f;
    for (int c = 0; c < NCHUNK; ++c) {
        car[(size_t)(c * NST + s) * 2]     = cr;
        car[(size_t)(c * NST + s) * 2 + 1] = ci;
        float er = ends[(size_t)(c * NST + s) * 2];
        float ei = ends[(size_t)(c * NST + s) * 2 + 1];
        float nr = fmaf(ar, cr, fmaf(-ai, ci, er));
        float ni = fmaf(ar, ci, fmaf( ai, cr, ei));
        cr = nr; ci = ni;
    }
}

// ---------- scan pass 2: full scan from carry, write H bf16 (in-place) ----
__global__ __launch_bounds__(128)
void scan_h(unsigned int* __restrict__ Bu, const float* __restrict__ lam,
            const float* __restrict__ gam, const float* __restrict__ car) {
    const int s = blockIdx.y * 128 + threadIdx.x;
    const int c = blockIdx.x;
    const float lr = lam[s], li = lam[NST + s], g = gam[s];
    float hr = car[(size_t)(c * NST + s) * 2];
    float hi = car[(size_t)(c * NST + s) * 2 + 1];
    size_t base = (size_t)c * CHUNK * NST + s;
    #pragma unroll 4
    for (int t = 0; t < CHUNK; ++t) {
        unsigned int v = Bu[base + (size_t)t * NST];
        float br = g * bf2f(v & 0xffffu);
        float bi = g * bf2f(v >> 16);
        float nr = fmaf(lr, hr, fmaf(-li, hi, br));
        float ni = fmaf(lr, hi, fmaf( li, hr, bi));
        hr = nr; hi = ni;
        Bu[base + (size_t)t * NST] =
            (unsigned int)f2bf(hr) | ((unsigned int)f2bf(hi) << 16);
    }
}

// ---------------- GEMM2: Y = H @ W2^T + D*x ----------------
__global__ __launch_bounds__(256)
void gemm2(const unsigned short* __restrict__ H, const unsigned short* __restrict__ W2,
           float* __restrict__ Y, const float* __restrict__ Dv,
           const float* __restrict__ Xf) {
    const int K = 1024, N = 1024;
    __shared__ __align__(16) unsigned short As[128 * 32];
    __shared__ __align__(16) unsigned short Bs[128 * 32];

    const int tid  = threadIdx.x;
    const int lane = tid & 63;
    const int wave = tid >> 6;
    const int wr   = wave >> 1, wc = wave & 1;

    const int lin   = blockIdx.y * gridDim.x + blockIdx.x;
    const int n_new = (lin & 7) * 128 + (lin >> 3);
    const int bx = n_new & 7, by = n_new >> 3;
    const int m0 = by * 128, n0 = bx * 128;

    const int srow = tid >> 2;
    const int skb  = (tid & 3) * 8;

    const unsigned short* Ag0 = H  + (size_t)(m0 + srow) * K + skb;
    const unsigned short* Ag1 = Ag0 + (size_t)64 * K;
    const unsigned short* Bg0 = W2 + (size_t)(n0 + srow) * K + skb;
    const unsigned short* Bg1 = Bg0 + (size_t)64 * K;

    f32x4 acc[4][4] = {};

    uint4 ra0 = *(const uint4*)Ag0;
    uint4 ra1 = *(const uint4*)Ag1;
    uint4 rb0 = *(const uint4*)Bg0;
    uint4 rb1 = *(const uint4*)Bg1;

    const int fr = lane & 15;
    const int fk = (lane >> 4) * 8;

    for (int k0 = 0; k0 < K; k0 += 32) {
        __syncthreads();
        *(uint4*)&As[srow * 32 + skb]        = ra0;
        *(uint4*)&As[(64 + srow) * 32 + skb] = ra1;
        *(uint4*)&Bs[srow * 32 + skb]        = rb0;
        *(uint4*)&Bs[(64 + srow) * 32 + skb] = rb1;
        __syncthreads();
        if (k0 + 32 < K) {
            ra0 = *(const uint4*)(Ag0 + k0 + 32);
            ra1 = *(const uint4*)(Ag1 + k0 + 32);
            rb0 = *(const uint4*)(Bg0 + k0 + 32);
            rb1 = *(const uint4*)(Bg1 + k0 + 32);
        }
        s16x8 af[4], bfq[4];
        #pragma unroll
        for (int i = 0; i < 4; ++i)
            af[i] = *(const s16x8*)&As[(wr * 64 + i * 16 + fr) * 32 + fk];
        #pragma unroll
        for (int j = 0; j < 4; ++j)
            bfq[j] = *(const s16x8*)&Bs[(wc * 64 + j * 16 + fr) * 32 + fk];
        #pragma unroll
        for (int i = 0; i < 4; ++i)
            #pragma unroll
            for (int j = 0; j < 4; ++j)
                mfma16(acc[i][j], af[i], bfq[j]);
    }

    const int crow = (lane >> 4) * 4;
    const int ccol = lane & 15;
    #pragma unroll
    for (int i = 0; i < 4; ++i) {
        #pragma unroll
        for (int j = 0; j < 4; ++j) {
            const int mbase = m0 + wr * 64 + i * 16 + crow;
            const int n     = n0 + wc * 64 + j * 16 + ccol;
            #pragma unroll
            for (int r = 0; r < 4; ++r) {
                const int m = mbase + r;
                Y[(size_t)m * N + n] = acc[i][j][r] + Dv[n] * Xf[(size_t)m * N + n];
            }
        }
    }
}

extern "C" void kernel_launch(void* const* d_in, const int* in_sizes, int n_in,
                              void* d_out, int out_size, void* d_ws, size_t ws_size,
                              hipStream_t stream) {
    const float* X         = (const float*)d_in[0];
    const float* nu_log    = (const float*)d_in[1];
    const float* theta_log = (const float*)d_in[2];
    const float* gamma_log = (const float*)d_in[3];
    const float* Bre       = (const float*)d_in[4];
    const float* Bim       = (const float*)d_in[5];
    const float* Cre       = (const float*)d_in[6];
    const float* Cim       = (const float*)d_in[7];
    const float* Dv        = (const float*)d_in[8];
    float* Y = (float*)d_out;

    char* ws = (char*)d_ws;
    size_t off = 0;
    unsigned short* Bu  = (unsigned short*)(ws + off); off += (size_t)L_SEQ * 1024 * 2;   // 32MB
    unsigned short* W1  = (unsigned short*)(ws + off); off += (size_t)DMODEL * DMODEL * 2; // 2MB
    unsigned short* W2  = (unsigned short*)(ws + off); off += (size_t)DMODEL * DMODEL * 2; // 2MB
    float* lam  = (float*)(ws + off); off += 1024 * 4;
    float* lamT = (float*)(ws + off); off += 1024 * 4;
    float* gam  = (float*)(ws + off); off += 512 * 4;
    float* ends = (float*)(ws + off); off += (size_t)NCHUNK * NST * 2 * 4;  // 512KB
    float* car  = (float*)(ws + off); off += (size_t)NCHUNK * NST * 2 * 4;  // 512KB

    setup_params<<<1, NST, 0, stream>>>(nu_log, theta_log, gamma_log, lam, lamT, gam);
    pack_w1<<<(DMODEL * DMODEL) / 256, 256, 0, stream>>>(Bre, Bim, W1);
    pack_w2<<<(DMODEL * DMODEL) / 256, 256, 0, stream>>>(Cre, Cim, W2);

    dim3 gg(8, 128);
    gemm1<<<gg, 256, 0, stream>>>(X, W1, Bu);

    dim3 gs(NCHUNK, 4);   // 128 chunks x 4 state-groups of 128
    scan_ends<<<gs, 128, 0, stream>>>((const unsigned int*)Bu, lam, gam, ends);
    scan_carry<<<1, NST, 0, stream>>>(ends, lamT, car);
    scan_h<<<gs, 128, 0, stream>>>((unsigned int*)Bu, lam, gam, car);

    gemm2<<<gg, 256, 0, stream>>>(Bu, W2, Y, Dv, X);
}